// Round 13
// baseline (1416.806 us; speedup 1.0000x reference)
//
#include <hip/hip_runtime.h>

// ---------------- workspace layout (float offsets) ----------------
#define WS_SEQ      0LL          // [3][16384][128]
#define WS_XGGRU    6291456LL    // [6][16384][192]
#define WS_X        0LL          // [3][16384][128]
#define WS_TSTEP    18874368LL   // [16384][384]
#define WS_S        6291456LL    // [192][65536] scores (3 pairs x 64 batch)
#define WS_XGLSTM   0LL          // [2][16384][512]
#define WS_SF       16777216LL   // [16384][256]
#define WS_XGRGN    0LL          // [2][16384][384]
#define WS_OUT0     20971520LL   // [2][64][128]

__device__ __forceinline__ float sigf(float x) {
    return __builtin_amdgcn_rcpf(1.f + __expf(-x));
}
__device__ __forceinline__ float tanhfast(float x) {
    float e = __expf(2.f * x);
    return 1.f - 2.f * __builtin_amdgcn_rcpf(e + 1.f);
}
// readlane: lane index uniform (unrolled loops -> compile-time constants)
__device__ __forceinline__ float rl(float v, int i) {
    return __int_as_float(__builtin_amdgcn_readlane(__float_as_int(v), i));
}

// 16-float register vector (single SSA value = 16 VGPRs, no alloca)
typedef float vf16 __attribute__((ext_vector_type(16)));
// 2-float register vector -> even-aligned VGPR pair (v_pk_fma operand)
typedef float vf2 __attribute__((ext_vector_type(2)));

#define LD16(V, P, S) { _Pragma("unroll") \
    for (int _j = 0; _j < 16; ++_j) (V)[_j] = (P)[_j * (S)]; }
#define DOT16(ACC, V, H, B) { _Pragma("unroll") \
    for (int _j = 0; _j < 16; ++_j) (ACC) = fmaf(rl((H), (B) + _j), (V)[_j], (ACC)); }

// ---------------- XCD-aware bijective block remap (m157/T1) ------------------
__device__ __forceinline__ void xcd_map(int& bx, int& by, int& bz) {
    int nx = gridDim.x, ny = gridDim.y;
    int n = nx * ny * gridDim.z;
    int flat = blockIdx.x + nx * (blockIdx.y + ny * blockIdx.z);
    int cpx = n >> 3;
    int w = (flat & 7) * cpx + (flat >> 3);
    bx = w % nx; w /= nx;
    by = w % ny; bz = w / ny;
}

// ---------------- shared fp32 GEMM body: 128x64 tile, 2 waves, 8x8 micro -----
// R8 pipeline (single LDS buffer, register prefetch of next K-tile after the
// barrier, two barriers per tile), tile grown to 128 rows with 2 waves:
// staging instructions per FLOP -25%, barriers per FLOP halved. Per-wave
// micro & per-element k-order identical -> bit-identical results.
__device__ __forceinline__ void gemm_body(
    int m0, int n0,
    const float* __restrict__ Ab, int lda, const int* __restrict__ idx,
    const float* __restrict__ Wb, int wld, int wtrans,
    const float* __restrict__ bb,
    const float* __restrict__ initsrc, int ldi,
    float* __restrict__ Cb, int ldc,
    int K, float alpha, int accum)
{
    int t = threadIdx.x;                 // 0..127
    int lane = t & 63;
    int tx = lane & 7, ty = lane >> 3;
    int rbase = (t >> 6) * 64 + ty * 8;  // wave 0: rows 0..63, wave 1: 64..127

    __shared__ __align__(16) float As[16][132];
    __shared__ __align__(16) float Ws[16][68];

    vf2 acc2[8][4];
#pragma unroll
    for (int i = 0; i < 8; ++i)
#pragma unroll
        for (int j = 0; j < 4; ++j) acc2[i][j] = (vf2){0.f, 0.f};

    long long arow[4];
#pragma unroll
    for (int i = 0; i < 4; ++i) {
        int m = (t + i * 128) >> 2;
        arow[i] = idx ? (long long)idx[m0 + m] : (long long)(m0 + m);
    }
    const bool a_vec = ((lda & 3) == 0);

    auto loadA = [&](int k0, float4* r) {
#pragma unroll
        for (int i = 0; i < 4; ++i) {
            int j = t + i * 128;
            int kq = j & 3;
            int kk = k0 + kq * 4;
            const float* p = Ab + arow[i] * (long long)lda + kk;
            float4 v = {0.f, 0.f, 0.f, 0.f};
            if (a_vec && kk + 3 < K) {
                v = *(const float4*)p;
            } else {
                if (kk + 0 < K) v.x = p[0];
                if (kk + 1 < K) v.y = p[1];
                if (kk + 2 < K) v.z = p[2];
                if (kk + 3 < K) v.w = p[3];
            }
            r[i] = v;
        }
    };
    auto loadW = [&](int k0, float4* r) {
        if (!wtrans) {
#pragma unroll
            for (int i = 0; i < 2; ++i) {
                int j = t + i * 128;
                int k = j >> 4, nq = j & 15;
                float4 v = {0.f, 0.f, 0.f, 0.f};
                if (k0 + k < K)
                    v = *(const float4*)(Wb + (long long)(k0 + k) * wld + n0 + nq * 4);
                r[i] = v;
            }
        } else {
#pragma unroll
            for (int i = 0; i < 2; ++i) {
                int j = t + i * 128;
                int n = j >> 2, kq = j & 3;
                int kk = k0 + kq * 4;
                const float* p = Wb + (long long)(n0 + n) * wld + kk;
                float4 v = {0.f, 0.f, 0.f, 0.f};
                if (kk + 3 < K) v = *(const float4*)p;
                else {
                    if (kk + 0 < K) v.x = p[0];
                    if (kk + 1 < K) v.y = p[1];
                    if (kk + 2 < K) v.z = p[2];
                    if (kk + 3 < K) v.w = p[3];
                }
                r[i] = v;
            }
        }
    };

    float4 aR[4], wR[2];
    loadA(0, aR);
    loadW(0, wR);

    for (int k0 = 0; k0 < K; k0 += 16) {
        // ---- LDS writes from the prefetched registers ----
#pragma unroll
        for (int i = 0; i < 4; ++i) {
            int j = t + i * 128;
            int m = j >> 2, kq = j & 3;
            As[kq * 4 + 0][m] = aR[i].x; As[kq * 4 + 1][m] = aR[i].y;
            As[kq * 4 + 2][m] = aR[i].z; As[kq * 4 + 3][m] = aR[i].w;
        }
        if (!wtrans) {
#pragma unroll
            for (int i = 0; i < 2; ++i) {
                int j = t + i * 128;
                int k = j >> 4, nq = j & 15;
                *(float4*)&Ws[k][nq * 4] = wR[i];
            }
        } else {
#pragma unroll
            for (int i = 0; i < 2; ++i) {
                int j = t + i * 128;
                int n = j >> 2, kq = j & 3;
                Ws[kq * 4 + 0][n] = wR[i].x; Ws[kq * 4 + 1][n] = wR[i].y;
                Ws[kq * 4 + 2][n] = wR[i].z; Ws[kq * 4 + 3][n] = wR[i].w;
            }
        }
        __syncthreads();
        // ---- issue next tile's global loads (latency hides under compute) ----
        if (k0 + 16 < K) {
            loadA(k0 + 16, aR);
            loadW(k0 + 16, wR);
        }
        // ---- 16-k inner compute ----
#pragma unroll
        for (int k = 0; k < 16; ++k) {
            float4 a0 = *(const float4*)&As[k][rbase];
            float4 a1 = *(const float4*)&As[k][rbase + 4];
            float4 b0 = *(const float4*)&Ws[k][tx * 8];
            float4 b1 = *(const float4*)&Ws[k][tx * 8 + 4];
            float av[8] = {a0.x, a0.y, a0.z, a0.w, a1.x, a1.y, a1.z, a1.w};
            vf2 bv[4];
            bv[0] = (vf2){b0.x, b0.y}; bv[1] = (vf2){b0.z, b0.w};
            bv[2] = (vf2){b1.x, b1.y}; bv[3] = (vf2){b1.z, b1.w};
#pragma unroll
            for (int i = 0; i < 8; ++i) {
                vf2 a2 = {av[i], av[i]};
#pragma unroll
                for (int j = 0; j < 4; ++j)
                    acc2[i][j] = __builtin_elementwise_fma(a2, bv[j], acc2[i][j]);
            }
        }
        __syncthreads();
    }

#pragma unroll
    for (int i = 0; i < 8; ++i) {
        long long gm = m0 + rbase + i;
#pragma unroll
        for (int jq = 0; jq < 2; ++jq) {
            int col = n0 + tx * 8 + jq * 4;
            float* cp = Cb + gm * ldc + col;
            float4 v;
            v.x = alpha * acc2[i][jq * 2 + 0][0];
            v.y = alpha * acc2[i][jq * 2 + 0][1];
            v.z = alpha * acc2[i][jq * 2 + 1][0];
            v.w = alpha * acc2[i][jq * 2 + 1][1];
            if (bb) {
                const float* bp = bb + col;
                v.x += bp[0]; v.y += bp[1]; v.z += bp[2]; v.w += bp[3];
            }
            if (initsrc) {
                // col is already the column within the q-slice (ldi-wide)
                const float* ip = initsrc + gm * (long long)ldi + col;
                v.x += ip[0]; v.y += ip[1]; v.z += ip[2]; v.w += ip[3];
            }
            if (accum) {
                float4 o = *(const float4*)cp;
                v.x += o.x; v.y += o.y; v.z += o.z; v.w += o.w;
            }
            *(float4*)cp = v;
        }
    }
}

// ---------------- generic GEMM launcher-kernel (XCD-swizzled) ----------------
__global__ __launch_bounds__(128) void gemm_k(
    const float* __restrict__ A, long long a_z, int a_zdiv, int lda,
    const int* __restrict__ idx,
    const float* __restrict__ W, long long w_z, int wld, int wtrans,
    const float* __restrict__ bias, int bias_z,
    float* __restrict__ C, long long c_z, int ldc,
    int K, float alpha, int accum)
{
    int bx, by, bz;
    xcd_map(bx, by, bz);
    int z = bz;
    gemm_body(by * 128, bx * 64,
              A + (long long)(z / a_zdiv) * a_z, lda, idx,
              W + (long long)z * w_z, wld, wtrans,
              bias ? bias + (long long)z * bias_z : nullptr, nullptr, 0,
              C + (long long)z * c_z, ldc, K, alpha, accum);
}

// ---------------- fused modality projections (one launch, z-switch) ---------
__global__ __launch_bounds__(128) void proj3_k(
    const int* __restrict__ sent, const float* __restrict__ emb,
    const float* __restrict__ acoustic, const float* __restrict__ video,
    const float* __restrict__ plW, const float* __restrict__ plb,
    const float* __restrict__ paW, const float* __restrict__ pab,
    const float* __restrict__ pvW, const float* __restrict__ pvb,
    float* __restrict__ seq)
{
    int bx, by, bz;
    xcd_map(bx, by, bz);
    int z = bz;
    const float* A; int lda; const int* ix; const float* W; const float* bi;
    float* C; int K;
    if (z == 0) { A = emb;      lda = 300; ix = sent;    W = plW; bi = plb;
                  C = seq;               K = 300; }
    else if (z == 1) { A = acoustic; lda = 74;  ix = nullptr; W = paW; bi = pab;
                  C = seq + 2097152;     K = 74; }
    else        { A = video;    lda = 35;  ix = nullptr; W = pvW; bi = pvb;
                  C = seq + 4194304;     K = 35; }
    gemm_body(by * 128, bx * 64, A, lda, ix, W, 128, 0, bi, nullptr, 0,
              C, 128, K, 1.f, 0);
}

// ---------------- batched attention score: S[z] = scale * q_b @ kv_b^T ------
__global__ __launch_bounds__(128) void att_score_k(
    const float* __restrict__ X, float* __restrict__ S,
    int q0, int q1, int q2, int k0, int k1, int k2)
{
    int bx, by, bz;
    xcd_map(bx, by, bz);
    int z = bz;
    int pair = z >> 6, b = z & 63;
    int qi = pair == 0 ? q0 : (pair == 1 ? q1 : q2);
    int ki = pair == 0 ? k0 : (pair == 1 ? k1 : k2);
    gemm_body(by * 128, bx * 64,
              X + (long long)qi * 2097152 + (long long)b * 32768, 128, nullptr,
              X + (long long)ki * 2097152 + (long long)b * 32768, 128, 1,
              nullptr, nullptr, 0,
              S + (long long)z * 65536, 256, 128, 0.08838834764831845f, 0);
}

// ---------------- batched attention apply ------------------------------------
// doinit=1 (round 1): tstep = x_q + P@kv  (init from X, no C readback)
// doinit=0 (round 2): tstep += P@kv      (accumulate)
__global__ __launch_bounds__(128) void att_apply_k(
    const float* __restrict__ S, const float* __restrict__ X,
    float* __restrict__ tstep,
    int q0, int q1, int q2, int k0, int k1, int k2, int doinit)
{
    int bx, by, bz;
    xcd_map(bx, by, bz);
    int z = bz;
    int pair = z >> 6, b = z & 63;
    int qi = pair == 0 ? q0 : (pair == 1 ? q1 : q2);
    int ki = pair == 0 ? k0 : (pair == 1 ? k1 : k2);
    const float* initsrc = doinit
        ? X + (long long)qi * 2097152 + (long long)b * 32768 : nullptr;
    gemm_body(by * 128, bx * 64,
              S + (long long)z * 65536, 256, nullptr,
              X + (long long)ki * 2097152 + (long long)b * 32768, 128, 0,
              nullptr, initsrc, 128,
              tstep + (long long)qi * 128 + (long long)b * 98304, 384,
              256, 1.f, doinit ? 0 : 1);
}

// ---------------- softmax over rows of 256 (one wave per row) ----------------
__global__ __launch_bounds__(256) void softmax_k(float* __restrict__ S)
{
    int wave = threadIdx.x >> 6, lane = threadIdx.x & 63;
    int row = blockIdx.x * 4 + wave;
    float* p = S + (long long)row * 256;
    float v[4];
    float mx = -1e30f;
#pragma unroll
    for (int i = 0; i < 4; ++i) { v[i] = p[lane + i * 64]; mx = fmaxf(mx, v[i]); }
#pragma unroll
    for (int off = 32; off > 0; off >>= 1) mx = fmaxf(mx, __shfl_xor(mx, off));
    float sum = 0.f;
#pragma unroll
    for (int i = 0; i < 4; ++i) { v[i] = __expf(v[i] - mx); sum += v[i]; }
#pragma unroll
    for (int off = 32; off > 0; off >>= 1) sum += __shfl_xor(sum, off);
    float inv = 1.f / sum;
#pragma unroll
    for (int i = 0; i < 4; ++i) p[lane + i * 64] = v[i] * inv;
}

// ---------------- GRU recurrence: 192 thr, replicated tail, 1 barrier/step ---
// (R1 form: best measured for GRU)
__global__ __launch_bounds__(192) void gru_rec_k(const float* __restrict__ xg,
                                                 const float* __restrict__ Wh,
                                                 const float* __restrict__ bh,
                                                 float* __restrict__ xout)
{
    int b = blockIdx.x, z = blockIdx.y;
    int m = z >> 1, d = z & 1;
    int tid = threadIdx.x, lane = tid & 63;
    int c = tid;                        // gate column 0..191
    const float* Whz = Wh + (long long)z * 12288;   // [64][192]
    const float* wp = Whz + c;
    vf16 W0, W1, W2, W3;
    LD16(W0, wp + 0 * 16 * 192, 192); LD16(W1, wp + 1 * 16 * 192, 192);
    LD16(W2, wp + 2 * 16 * 192, 192); LD16(W3, wp + 3 * 16 * 192, 192);
    float bias = bh[z * 192 + c];       // hidden bias folds into h-dot

    __shared__ float g[2][192];
    int n = lane;                       // h element this lane replicates
    float h = 0.f;
    const float* xgb = xg + (long long)z * 3145728 + (long long)b * 49152;
    float* xob = xout + (long long)m * 2097152 + (long long)b * 32768 + d * 64;
    int tt0 = d ? 255 : 0;
    const float* xr0 = xgb + tt0 * 192;
    float x_r = xr0[n], x_z = xr0[64 + n], x_n = xr0[128 + n];

#pragma unroll 1
    for (int t = 0; t < 256; ++t) {
        int tt = d ? 255 - t : t;
        float nx_r = 0, nx_z = 0, nx_n = 0;
        if (t < 255) {
            const float* xr = xgb + (d ? tt - 1 : tt + 1) * 192;
            nx_r = xr[n]; nx_z = xr[64 + n]; nx_n = xr[128 + n];
        }
        float s0 = bias, s1 = 0.f, s2 = 0.f, s3 = 0.f;
        DOT16(s0, W0, h, 0);  DOT16(s1, W1, h, 16);
        DOT16(s2, W2, h, 32); DOT16(s3, W3, h, 48);
        g[t & 1][c] = (s0 + s1) + (s2 + s3);
        __syncthreads();
        const float* gp = g[t & 1];
        float r  = sigf(x_r + gp[n]);
        float zz = sigf(x_z + gp[64 + n]);
        float nn = tanhfast(x_n + r * gp[128 + n]);   // bh(n) inside r*(), x outside
        h = (1.f - zz) * nn + zz * h;
        if (c < 64) xob[tt * 128 + n] = h;            // wave 0 stores
        x_r = nx_r; x_z = nx_z; x_n = nx_n;
    }
}

// ---------------- LSTM recurrence: 512 thr, 72/128 k-rows LDS-resident -------
// (R6 form: best measured, ~280 us)
__global__ __launch_bounds__(512) void lstm_rec_k(const float* __restrict__ xg,
                                                  const float* __restrict__ Wh,
                                                  const float* __restrict__ bh,
                                                  float* __restrict__ sf)
{
    int b = blockIdx.x, d = blockIdx.y;
    int tid = threadIdx.x, lane = tid & 63;
    int kh = tid >> 8;                  // k-half (wave-uniform: waves 0-3 / 4-7)
    int cp = tid & 255;                 // column pair -> cols 2cp, 2cp+1
    const float* Whz = Wh + (long long)d * 65536;   // [128][512]

    __shared__ __align__(16) float wlds[36864];     // 72 rows x 512
    __shared__ float part[2][1024];
    // LDS rows 0..35 <- Wh rows 0..35 (kh0), rows 36..71 <- Wh rows 64..99 (kh1)
    for (int i = tid; i < 9216; i += 512) {
        int row = i >> 7, c4 = (i & 127) << 2;
        int srow = row < 36 ? row : row + 28;
        *(float4*)&wlds[row * 512 + c4] = *(const float4*)(Whz + srow * 512 + c4);
    }
    const float* wl  = wlds + (kh * 36) * 512 + 2 * cp;
    const float* wpg = Whz + (long long)(kh * 64 + 36) * 512 + 2 * cp;

    int n = kh * 64 + lane;             // h element this lane replicates
    float h = 0.f, cst = 0.f;
    const float* xgb = xg + (long long)d * 8388608 + (long long)b * 131072;
    float* sfb = sf + (long long)b * 65536 + d * 128;

    vf2 bias2 = {0.f, 0.f}, xc2 = {0.f, 0.f};
    if (kh == 0) {                      // fold x+bias into kh=0 dot init
        bias2 = *(const vf2*)(bh + d * 512 + 2 * cp);
        int tt0 = d ? 255 : 0;
        xc2 = *(const vf2*)(xgb + tt0 * 512 + 2 * cp);
    }
    __syncthreads();                    // wlds ready

#pragma unroll 1
    for (int t = 0; t < 256; ++t) {
        int tt = d ? 255 - t : t;
        vf2 nxc2 = {0.f, 0.f};
        if (kh == 0 && t < 255)
            nxc2 = *(const vf2*)(xgb + (d ? tt - 1 : tt + 1) * 512 + 2 * cp);
        vf2 a0 = xc2 + bias2, a1 = {0.f, 0.f};
#pragma unroll
        for (int r = 0; r < 36; ++r) {  // LDS rows: k = r
            float hs = rl(h, r);
            vf2 hb = {hs, hs};
            vf2 w = *(const vf2*)(wl + r * 512);
            if (r & 1) a1 = __builtin_elementwise_fma(hb, w, a1);
            else       a0 = __builtin_elementwise_fma(hb, w, a0);
        }
#pragma unroll
        for (int r = 0; r < 28; ++r) {  // global rows: k = 36 + r
            float hs = rl(h, 36 + r);
            vf2 hb = {hs, hs};
            vf2 w = *(const vf2*)(wpg + r * 512);
            if (r & 1) a1 = __builtin_elementwise_fma(hb, w, a1);
            else       a0 = __builtin_elementwise_fma(hb, w, a0);
        }
        *(vf2*)&part[t & 1][kh * 512 + 2 * cp] = a0 + a1;
        __syncthreads();
        const float* p = part[t & 1];
        float iv = p[n]       + p[512 + n];
        float fv = p[128 + n] + p[512 + 128 + n];
        float gv = p[256 + n] + p[512 + 256 + n];
        float ov = p[384 + n] + p[512 + 384 + n];
        cst = sigf(fv) * cst + sigf(iv) * tanhfast(gv);
        h = sigf(ov) * tanhfast(cst);
        if (cp < 64) sfb[tt * 256 + n] = h;   // waves 0 and 4 store n=0..127
        xc2 = nxc2;
    }
}

// ---------------- RGN recurrence: 768 thr, replicated tail, 1 barrier --------
// (R1 form: best measured for RGN)
__global__ __launch_bounds__(768) void rgn_rec_k(const float* __restrict__ xg,
                                                 const float* __restrict__ Wh,
                                                 const float* __restrict__ state0,
                                                 const float* __restrict__ state1,
                                                 float* __restrict__ outbase)
{
    int b = blockIdx.x, d = blockIdx.y;
    int tid = threadIdx.x, lane = tid & 63;
    int kh = (tid >= 384) ? 1 : 0;      // wave-uniform (384 = 6 waves)
    int c  = tid - kh * 384;            // gate column 0..383
    const float* Whz = Wh + (long long)d * 49152;   // [128][384]
    const float* wp = Whz + (long long)(kh * 64) * 384 + c;
    vf16 W0, W1, W2, W3;
    LD16(W0, wp + 0 * 16 * 384, 384); LD16(W1, wp + 1 * 16 * 384, 384);
    LD16(W2, wp + 2 * 16 * 384, 384); LD16(W3, wp + 3 * 16 * 384, 384);

    __shared__ float part[2][768];
    int n = kh * 64 + lane;             // h element this lane replicates
    const float* st = d ? state1 : state0;
    float h = st[b * 128 + n];
    const float* xgb = xg + (long long)d * 6291456 + (long long)b * 98304;
    int tt0 = d ? 255 : 0;
    const float* xr0 = xgb + tt0 * 384;
    float x_r = xr0[n], x_z = xr0[128 + n], x_n = xr0[256 + n];

#pragma unroll 1
    for (int t = 0; t < 256; ++t) {
        int tt = d ? 255 - t : t;
        float nx_r = 0, nx_z = 0, nx_n = 0;
        if (t < 255) {
            const float* xr = xgb + (d ? tt - 1 : tt + 1) * 384;
            nx_r = xr[n]; nx_z = xr[128 + n]; nx_n = xr[256 + n];
        }
        float s0 = 0.f, s1 = 0.f, s2 = 0.f, s3 = 0.f;
        DOT16(s0, W0, h, 0);  DOT16(s1, W1, h, 16);
        DOT16(s2, W2, h, 32); DOT16(s3, W3, h, 48);
        part[t & 1][kh * 384 + c] = (s0 + s1) + (s2 + s3);
        __syncthreads();
        const float* p = part[t & 1];
        float pr = p[n]       + p[384 + n];
        float pz = p[128 + n] + p[384 + 128 + n];
        float pn = p[256 + n] + p[384 + 256 + n];
        float r  = sigf(x_r + pr);
        float zz = sigf(x_z + pz);
        float nn = tanhfast(x_n + r * pn);       // RGN: no hidden bias
        h = (1.f - zz) * nn + zz * h;
        x_r = nx_r; x_z = nx_z; x_n = nx_n;
    }
    if (c < 64) outbase[(long long)d * 8192 + b * 128 + n] = h;  // waves 0 & 6
}

// ---------------- final FC ----------------
__global__ __launch_bounds__(256) void fc_k(const float* __restrict__ o01,
                                            const float* __restrict__ f1W,
                                            const float* __restrict__ f1b,
                                            const float* __restrict__ f2W,
                                            const float* __restrict__ f2b,
                                            float* __restrict__ out)
{
    __shared__ float s[8192];
    __shared__ float h1[2048];
    int tid = threadIdx.x;
    for (int e = tid; e < 8192; e += 256) s[e] = o01[e] + o01[8192 + e];
    __syncthreads();
    for (int o = tid; o < 2048; o += 256) {
        int b = o >> 5, q = o & 31;
        float acc = f1b[q];
        for (int k = 0; k < 128; ++k) acc += s[b * 128 + k] * f1W[k * 32 + q];
        h1[o] = acc >= 0.f ? acc : 0.01f * acc;
    }
    __syncthreads();
    if (tid < 64) {
        float acc = f2b[0];
        for (int q = 0; q < 32; ++q) acc += h1[tid * 32 + q] * f2W[q];
        out[tid] = acc;
    }
}

// ============================ launch =========================================
extern "C" void kernel_launch(void* const* d_in, const int* in_sizes, int n_in,
                              void* d_out, int out_size, void* d_ws, size_t ws_size,
                              hipStream_t stream)
{
    const int*   sent     = (const int*)  d_in[0];
    const float* acoustic = (const float*)d_in[1];
    const float* video    = (const float*)d_in[2];
    const float* state0   = (const float*)d_in[3];
    const float* state1   = (const float*)d_in[4];
    const float* emb      = (const float*)d_in[5];
    const float* plW = (const float*)d_in[6],  *plb = (const float*)d_in[7];
    const float* paW = (const float*)d_in[8],  *pab = (const float*)d_in[9];
    const float* pvW = (const float*)d_in[10], *pvb = (const float*)d_in[11];
    const float* gWi = (const float*)d_in[12], *gWh = (const float*)d_in[13];
    const float* gbi = (const float*)d_in[14], *gbh = (const float*)d_in[15];
    const float* lWi = (const float*)d_in[16], *lWh = (const float*)d_in[17];
    const float* lbi = (const float*)d_in[18], *lbh = (const float*)d_in[19];
    const float* rWx = (const float*)d_in[20], *rWh = (const float*)d_in[21];
    const float* rb  = (const float*)d_in[22];
    const float* f1W = (const float*)d_in[23], *f1b = (const float*)d_in[24];
    const float* f2W = (const float*)d_in[25], *f2b = (const float*)d_in[26];
    float* ws  = (float*)d_ws;
    float* out = (float*)d_out;

    dim3 blk(128);

    // fused modality projections -> seq[3][16384][128]  (one launch)
    proj3_k<<<dim3(2, 128, 3), blk, 0, stream>>>(sent, emb, acoustic, video,
        plW, plb, paW, pab, pvW, pvb, ws + WS_SEQ);

    // GRU input projections, z = modality*2 + dir
    gemm_k<<<dim3(3, 128, 6), blk, 0, stream>>>(ws + WS_SEQ, 2097152, 2, 128, nullptr,
        gWi, 24576, 192, 0, gbi, 192, ws + WS_XGGRU, 3145728, 192, 128, 1.f, 0);

    // GRU recurrences -> x[3][16384][128]
    gru_rec_k<<<dim3(64, 6), dim3(192), 0, stream>>>(ws + WS_XGGRU, gWh, gbh, ws + WS_X);

    // attention: round 1 initializes tstep = x + att1, round 2 accumulates
    att_score_k<<<dim3(4, 2, 192), blk, 0, stream>>>(ws + WS_X, ws + WS_S,
        0, 1, 2, 1, 0, 0);
    softmax_k<<<dim3(12288), dim3(256), 0, stream>>>(ws + WS_S);
    att_apply_k<<<dim3(2, 2, 192), blk, 0, stream>>>(ws + WS_S, ws + WS_X,
        ws + WS_TSTEP, 0, 1, 2, 1, 0, 0, 1);
    att_score_k<<<dim3(4, 2, 192), blk, 0, stream>>>(ws + WS_X, ws + WS_S,
        0, 1, 2, 2, 2, 1);
    softmax_k<<<dim3(12288), dim3(256), 0, stream>>>(ws + WS_S);
    att_apply_k<<<dim3(2, 2, 192), blk, 0, stream>>>(ws + WS_S, ws + WS_X,
        ws + WS_TSTEP, 0, 1, 2, 2, 2, 1, 0);

    // LSTM input projections
    gemm_k<<<dim3(8, 128, 2), blk, 0, stream>>>(ws + WS_TSTEP, 0, 1, 384, nullptr,
        lWi, 196608, 512, 0, lbi, 512, ws + WS_XGLSTM, 8388608, 512, 384, 1.f, 0);

    // BiLSTM recurrences -> step_fusion[16384][256]
    lstm_rec_k<<<dim3(64, 2), dim3(512), 0, stream>>>(ws + WS_XGLSTM, lWh, lbh, ws + WS_SF);

    // RGN input projections
    gemm_k<<<dim3(6, 128, 2), blk, 0, stream>>>(ws + WS_SF, 0, 1, 256, nullptr,
        rWx, 98304, 384, 0, rb, 384, ws + WS_XGRGN, 6291456, 384, 256, 1.f, 0);

    // RGN recurrences -> out0/out1 [64][128]
    rgn_rec_k<<<dim3(64, 2), dim3(768), 0, stream>>>(ws + WS_XGRGN, rWh, state0, state1,
                                                     ws + WS_OUT0);

    // final FC -> d_out [64]
    fc_k<<<dim3(1), dim3(256), 0, stream>>>(ws + WS_OUT0, f1W, f1b, f2W, f2b, out);
}

// Round 14
// 1379.484 us; speedup vs baseline: 1.0271x; 1.0271x over previous
//
#include <hip/hip_runtime.h>

// ---------------- workspace layout (float offsets) ----------------
#define WS_SEQ      0LL          // [3][16384][128]
#define WS_XGGRU    6291456LL    // [6][16384][192]
#define WS_X        0LL          // [3][16384][128]
#define WS_TSTEP    18874368LL   // [16384][384]
#define WS_S        6291456LL    // [192][65536] scores (3 pairs x 64 batch)
#define WS_XGLSTM   0LL          // [2][16384][512]
#define WS_SF       16777216LL   // [16384][256]
#define WS_XGRGN    0LL          // [2][16384][384]
#define WS_OUT0     20971520LL   // [2][64][128]

__device__ __forceinline__ float sigf(float x) {
    return __builtin_amdgcn_rcpf(1.f + __expf(-x));
}
__device__ __forceinline__ float tanhfast(float x) {
    float e = __expf(2.f * x);
    return 1.f - 2.f * __builtin_amdgcn_rcpf(e + 1.f);
}
// readlane: lane index uniform (unrolled loops -> compile-time constants)
__device__ __forceinline__ float rl(float v, int i) {
    return __int_as_float(__builtin_amdgcn_readlane(__float_as_int(v), i));
}

// 16-float register vector (single SSA value = 16 VGPRs, no alloca)
typedef float vf16 __attribute__((ext_vector_type(16)));
// 2-float register vector -> even-aligned VGPR pair (v_pk_fma operand)
typedef float vf2 __attribute__((ext_vector_type(2)));

#define LD16(V, P, S) { _Pragma("unroll") \
    for (int _j = 0; _j < 16; ++_j) (V)[_j] = (P)[_j * (S)]; }
#define DOT16(ACC, V, H, B) { _Pragma("unroll") \
    for (int _j = 0; _j < 16; ++_j) (ACC) = fmaf(rl((H), (B) + _j), (V)[_j], (ACC)); }

// ---------------- XCD-aware bijective block remap (m157/T1) ------------------
__device__ __forceinline__ void xcd_map(int& bx, int& by, int& bz) {
    int nx = gridDim.x, ny = gridDim.y;
    int n = nx * ny * gridDim.z;
    int flat = blockIdx.x + nx * (blockIdx.y + ny * blockIdx.z);
    int cpx = n >> 3;
    int w = (flat & 7) * cpx + (flat >> 3);
    bx = w % nx; w /= nx;
    by = w % ny; bz = w / ny;
}

// ---------------- shared fp32 GEMM body: 64x64 tile, 1 wave, 8x8 micro -------
// R8/R12 structure (measured best): single LDS buffer, register prefetch of
// the next K-tile issued right after the barrier, two barriers per tile.
// Optional initsrc: epilogue adds initsrc[row*ldi+col] (col within slice).
__device__ __forceinline__ void gemm_body(
    int m0, int n0,
    const float* __restrict__ Ab, int lda, const int* __restrict__ idx,
    const float* __restrict__ Wb, int wld, int wtrans,
    const float* __restrict__ bb,
    const float* __restrict__ initsrc, int ldi,
    float* __restrict__ Cb, int ldc,
    int K, float alpha, int accum)
{
    int t = threadIdx.x;
    int tx = t & 7, ty = t >> 3;

    __shared__ __align__(16) float As[16][68];
    __shared__ __align__(16) float Ws[16][68];

    vf2 acc2[8][4];
#pragma unroll
    for (int i = 0; i < 8; ++i)
#pragma unroll
        for (int j = 0; j < 4; ++j) acc2[i][j] = (vf2){0.f, 0.f};

    long long arow[4];
#pragma unroll
    for (int i = 0; i < 4; ++i) {
        int m = (t + i * 64) >> 2;
        arow[i] = idx ? (long long)idx[m0 + m] : (long long)(m0 + m);
    }
    const bool a_vec = ((lda & 3) == 0);

    auto loadA = [&](int k0, float4* r) {
#pragma unroll
        for (int i = 0; i < 4; ++i) {
            int j = t + i * 64;
            int kq = j & 3;
            int kk = k0 + kq * 4;
            const float* p = Ab + arow[i] * (long long)lda + kk;
            float4 v = {0.f, 0.f, 0.f, 0.f};
            if (a_vec && kk + 3 < K) {
                v = *(const float4*)p;
            } else {
                if (kk + 0 < K) v.x = p[0];
                if (kk + 1 < K) v.y = p[1];
                if (kk + 2 < K) v.z = p[2];
                if (kk + 3 < K) v.w = p[3];
            }
            r[i] = v;
        }
    };
    auto loadW = [&](int k0, float4* r) {
        if (!wtrans) {
#pragma unroll
            for (int i = 0; i < 4; ++i) {
                int j = t + i * 64;
                int k = j >> 4, nq = j & 15;
                float4 v = {0.f, 0.f, 0.f, 0.f};
                if (k0 + k < K)
                    v = *(const float4*)(Wb + (long long)(k0 + k) * wld + n0 + nq * 4);
                r[i] = v;
            }
        } else {
#pragma unroll
            for (int i = 0; i < 4; ++i) {
                int j = t + i * 64;
                int n = j >> 2, kq = j & 3;
                int kk = k0 + kq * 4;
                const float* p = Wb + (long long)(n0 + n) * wld + kk;
                float4 v = {0.f, 0.f, 0.f, 0.f};
                if (kk + 3 < K) v = *(const float4*)p;
                else {
                    if (kk + 0 < K) v.x = p[0];
                    if (kk + 1 < K) v.y = p[1];
                    if (kk + 2 < K) v.z = p[2];
                    if (kk + 3 < K) v.w = p[3];
                }
                r[i] = v;
            }
        }
    };

    float4 aR[4], wR[4];
    loadA(0, aR);
    loadW(0, wR);

    for (int k0 = 0; k0 < K; k0 += 16) {
        // ---- LDS writes from the prefetched registers ----
#pragma unroll
        for (int i = 0; i < 4; ++i) {
            int j = t + i * 64;
            int m = j >> 2, kq = j & 3;
            As[kq * 4 + 0][m] = aR[i].x; As[kq * 4 + 1][m] = aR[i].y;
            As[kq * 4 + 2][m] = aR[i].z; As[kq * 4 + 3][m] = aR[i].w;
        }
        if (!wtrans) {
#pragma unroll
            for (int i = 0; i < 4; ++i) {
                int j = t + i * 64;
                int k = j >> 4, nq = j & 15;
                *(float4*)&Ws[k][nq * 4] = wR[i];
            }
        } else {
#pragma unroll
            for (int i = 0; i < 4; ++i) {
                int j = t + i * 64;
                int n = j >> 2, kq = j & 3;
                Ws[kq * 4 + 0][n] = wR[i].x; Ws[kq * 4 + 1][n] = wR[i].y;
                Ws[kq * 4 + 2][n] = wR[i].z; Ws[kq * 4 + 3][n] = wR[i].w;
            }
        }
        __syncthreads();
        // ---- issue next tile's global loads (latency hides under compute) ----
        if (k0 + 16 < K) {
            loadA(k0 + 16, aR);
            loadW(k0 + 16, wR);
        }
        // ---- 16-k inner compute ----
#pragma unroll
        for (int k = 0; k < 16; ++k) {
            float4 a0 = *(const float4*)&As[k][ty * 8];
            float4 a1 = *(const float4*)&As[k][ty * 8 + 4];
            float4 b0 = *(const float4*)&Ws[k][tx * 8];
            float4 b1 = *(const float4*)&Ws[k][tx * 8 + 4];
            float av[8] = {a0.x, a0.y, a0.z, a0.w, a1.x, a1.y, a1.z, a1.w};
            vf2 bv[4];
            bv[0] = (vf2){b0.x, b0.y}; bv[1] = (vf2){b0.z, b0.w};
            bv[2] = (vf2){b1.x, b1.y}; bv[3] = (vf2){b1.z, b1.w};
#pragma unroll
            for (int i = 0; i < 8; ++i) {
                vf2 a2 = {av[i], av[i]};
#pragma unroll
                for (int j = 0; j < 4; ++j)
                    acc2[i][j] = __builtin_elementwise_fma(a2, bv[j], acc2[i][j]);
            }
        }
        __syncthreads();
    }

#pragma unroll
    for (int i = 0; i < 8; ++i) {
        long long gm = m0 + ty * 8 + i;
#pragma unroll
        for (int jq = 0; jq < 2; ++jq) {
            int col = n0 + tx * 8 + jq * 4;
            float* cp = Cb + gm * ldc + col;
            float4 v;
            v.x = alpha * acc2[i][jq * 2 + 0][0];
            v.y = alpha * acc2[i][jq * 2 + 0][1];
            v.z = alpha * acc2[i][jq * 2 + 1][0];
            v.w = alpha * acc2[i][jq * 2 + 1][1];
            if (bb) {
                const float* bp = bb + col;
                v.x += bp[0]; v.y += bp[1]; v.z += bp[2]; v.w += bp[3];
            }
            if (initsrc) {
                // col is already the column within the q-slice (ldi-wide)
                const float* ip = initsrc + gm * (long long)ldi + col;
                v.x += ip[0]; v.y += ip[1]; v.z += ip[2]; v.w += ip[3];
            }
            if (accum) {
                float4 o = *(const float4*)cp;
                v.x += o.x; v.y += o.y; v.z += o.z; v.w += o.w;
            }
            *(float4*)cp = v;
        }
    }
}

// ---------------- generic GEMM launcher-kernel (XCD-swizzled) ----------------
__global__ __launch_bounds__(64) void gemm_k(
    const float* __restrict__ A, long long a_z, int a_zdiv, int lda,
    const int* __restrict__ idx,
    const float* __restrict__ W, long long w_z, int wld, int wtrans,
    const float* __restrict__ bias, int bias_z,
    float* __restrict__ C, long long c_z, int ldc,
    int K, float alpha, int accum)
{
    int bx, by, bz;
    xcd_map(bx, by, bz);
    int z = bz;
    gemm_body(by * 64, bx * 64,
              A + (long long)(z / a_zdiv) * a_z, lda, idx,
              W + (long long)z * w_z, wld, wtrans,
              bias ? bias + (long long)z * bias_z : nullptr, nullptr, 0,
              C + (long long)z * c_z, ldc, K, alpha, accum);
}

// ---------------- fused modality projections (one launch, z-switch) ---------
__global__ __launch_bounds__(64) void proj3_k(
    const int* __restrict__ sent, const float* __restrict__ emb,
    const float* __restrict__ acoustic, const float* __restrict__ video,
    const float* __restrict__ plW, const float* __restrict__ plb,
    const float* __restrict__ paW, const float* __restrict__ pab,
    const float* __restrict__ pvW, const float* __restrict__ pvb,
    float* __restrict__ seq)
{
    int bx, by, bz;
    xcd_map(bx, by, bz);
    int z = bz;
    const float* A; int lda; const int* ix; const float* W; const float* bi;
    float* C; int K;
    if (z == 0) { A = emb;      lda = 300; ix = sent;    W = plW; bi = plb;
                  C = seq;               K = 300; }
    else if (z == 1) { A = acoustic; lda = 74;  ix = nullptr; W = paW; bi = pab;
                  C = seq + 2097152;     K = 74; }
    else        { A = video;    lda = 35;  ix = nullptr; W = pvW; bi = pvb;
                  C = seq + 4194304;     K = 35; }
    gemm_body(by * 64, bx * 64, A, lda, ix, W, 128, 0, bi, nullptr, 0,
              C, 128, K, 1.f, 0);
}

// ---------------- batched attention score: S[z] = scale * q_b @ kv_b^T ------
__global__ __launch_bounds__(64) void att_score_k(
    const float* __restrict__ X, float* __restrict__ S,
    int q0, int q1, int q2, int k0, int k1, int k2)
{
    int bx, by, bz;
    xcd_map(bx, by, bz);
    int z = bz;
    int pair = z >> 6, b = z & 63;
    int qi = pair == 0 ? q0 : (pair == 1 ? q1 : q2);
    int ki = pair == 0 ? k0 : (pair == 1 ? k1 : k2);
    gemm_body(by * 64, bx * 64,
              X + (long long)qi * 2097152 + (long long)b * 32768, 128, nullptr,
              X + (long long)ki * 2097152 + (long long)b * 32768, 128, 1,
              nullptr, nullptr, 0,
              S + (long long)z * 65536, 256, 128, 0.08838834764831845f, 0);
}

// ---------------- batched attention apply ------------------------------------
// doinit=1 (round 1): tstep = x_q + P@kv  (init from X, no C readback)
// doinit=0 (round 2): tstep += P@kv      (accumulate)
__global__ __launch_bounds__(64) void att_apply_k(
    const float* __restrict__ S, const float* __restrict__ X,
    float* __restrict__ tstep,
    int q0, int q1, int q2, int k0, int k1, int k2, int doinit)
{
    int bx, by, bz;
    xcd_map(bx, by, bz);
    int z = bz;
    int pair = z >> 6, b = z & 63;
    int qi = pair == 0 ? q0 : (pair == 1 ? q1 : q2);
    int ki = pair == 0 ? k0 : (pair == 1 ? k1 : k2);
    const float* initsrc = doinit
        ? X + (long long)qi * 2097152 + (long long)b * 32768 : nullptr;
    gemm_body(by * 64, bx * 64,
              S + (long long)z * 65536, 256, nullptr,
              X + (long long)ki * 2097152 + (long long)b * 32768, 128, 0,
              nullptr, initsrc, 128,
              tstep + (long long)qi * 128 + (long long)b * 98304, 384,
              256, 1.f, doinit ? 0 : 1);
}

// ---------------- softmax over rows of 256 (one wave per row) ----------------
__global__ __launch_bounds__(256) void softmax_k(float* __restrict__ S)
{
    int wave = threadIdx.x >> 6, lane = threadIdx.x & 63;
    int row = blockIdx.x * 4 + wave;
    float* p = S + (long long)row * 256;
    float v[4];
    float mx = -1e30f;
#pragma unroll
    for (int i = 0; i < 4; ++i) { v[i] = p[lane + i * 64]; mx = fmaxf(mx, v[i]); }
#pragma unroll
    for (int off = 32; off > 0; off >>= 1) mx = fmaxf(mx, __shfl_xor(mx, off));
    float sum = 0.f;
#pragma unroll
    for (int i = 0; i < 4; ++i) { v[i] = __expf(v[i] - mx); sum += v[i]; }
#pragma unroll
    for (int off = 32; off > 0; off >>= 1) sum += __shfl_xor(sum, off);
    float inv = 1.f / sum;
#pragma unroll
    for (int i = 0; i < 4; ++i) p[lane + i * 64] = v[i] * inv;
}

// ---------------- GRU recurrence: 192 thr, replicated tail, 1 barrier/step ---
// (R1 form: best measured for GRU)
__global__ __launch_bounds__(192) void gru_rec_k(const float* __restrict__ xg,
                                                 const float* __restrict__ Wh,
                                                 const float* __restrict__ bh,
                                                 float* __restrict__ xout)
{
    int b = blockIdx.x, z = blockIdx.y;
    int m = z >> 1, d = z & 1;
    int tid = threadIdx.x, lane = tid & 63;
    int c = tid;                        // gate column 0..191
    const float* Whz = Wh + (long long)z * 12288;   // [64][192]
    const float* wp = Whz + c;
    vf16 W0, W1, W2, W3;
    LD16(W0, wp + 0 * 16 * 192, 192); LD16(W1, wp + 1 * 16 * 192, 192);
    LD16(W2, wp + 2 * 16 * 192, 192); LD16(W3, wp + 3 * 16 * 192, 192);
    float bias = bh[z * 192 + c];       // hidden bias folds into h-dot

    __shared__ float g[2][192];
    int n = lane;                       // h element this lane replicates
    float h = 0.f;
    const float* xgb = xg + (long long)z * 3145728 + (long long)b * 49152;
    float* xob = xout + (long long)m * 2097152 + (long long)b * 32768 + d * 64;
    int tt0 = d ? 255 : 0;
    const float* xr0 = xgb + tt0 * 192;
    float x_r = xr0[n], x_z = xr0[64 + n], x_n = xr0[128 + n];

#pragma unroll 1
    for (int t = 0; t < 256; ++t) {
        int tt = d ? 255 - t : t;
        float nx_r = 0, nx_z = 0, nx_n = 0;
        if (t < 255) {
            const float* xr = xgb + (d ? tt - 1 : tt + 1) * 192;
            nx_r = xr[n]; nx_z = xr[64 + n]; nx_n = xr[128 + n];
        }
        float s0 = bias, s1 = 0.f, s2 = 0.f, s3 = 0.f;
        DOT16(s0, W0, h, 0);  DOT16(s1, W1, h, 16);
        DOT16(s2, W2, h, 32); DOT16(s3, W3, h, 48);
        g[t & 1][c] = (s0 + s1) + (s2 + s3);
        __syncthreads();
        const float* gp = g[t & 1];
        float r  = sigf(x_r + gp[n]);
        float zz = sigf(x_z + gp[64 + n]);
        float nn = tanhfast(x_n + r * gp[128 + n]);   // bh(n) inside r*(), x outside
        h = (1.f - zz) * nn + zz * h;
        if (c < 64) xob[tt * 128 + n] = h;            // wave 0 stores
        x_r = nx_r; x_z = nx_z; x_n = nx_n;
    }
}

// ---------------- LSTM recurrence: 512 thr, 72/128 k-rows LDS-resident -------
// (R6 form: best measured, ~283 us)
__global__ __launch_bounds__(512) void lstm_rec_k(const float* __restrict__ xg,
                                                  const float* __restrict__ Wh,
                                                  const float* __restrict__ bh,
                                                  float* __restrict__ sf)
{
    int b = blockIdx.x, d = blockIdx.y;
    int tid = threadIdx.x, lane = tid & 63;
    int kh = tid >> 8;                  // k-half (wave-uniform: waves 0-3 / 4-7)
    int cp = tid & 255;                 // column pair -> cols 2cp, 2cp+1
    const float* Whz = Wh + (long long)d * 65536;   // [128][512]

    __shared__ __align__(16) float wlds[36864];     // 72 rows x 512
    __shared__ float part[2][1024];
    // LDS rows 0..35 <- Wh rows 0..35 (kh0), rows 36..71 <- Wh rows 64..99 (kh1)
    for (int i = tid; i < 9216; i += 512) {
        int row = i >> 7, c4 = (i & 127) << 2;
        int srow = row < 36 ? row : row + 28;
        *(float4*)&wlds[row * 512 + c4] = *(const float4*)(Whz + srow * 512 + c4);
    }
    const float* wl  = wlds + (kh * 36) * 512 + 2 * cp;
    const float* wpg = Whz + (long long)(kh * 64 + 36) * 512 + 2 * cp;

    int n = kh * 64 + lane;             // h element this lane replicates
    float h = 0.f, cst = 0.f;
    const float* xgb = xg + (long long)d * 8388608 + (long long)b * 131072;
    float* sfb = sf + (long long)b * 65536 + d * 128;

    vf2 bias2 = {0.f, 0.f}, xc2 = {0.f, 0.f};
    if (kh == 0) {                      // fold x+bias into kh=0 dot init
        bias2 = *(const vf2*)(bh + d * 512 + 2 * cp);
        int tt0 = d ? 255 : 0;
        xc2 = *(const vf2*)(xgb + tt0 * 512 + 2 * cp);
    }
    __syncthreads();                    // wlds ready

#pragma unroll 1
    for (int t = 0; t < 256; ++t) {
        int tt = d ? 255 - t : t;
        vf2 nxc2 = {0.f, 0.f};
        if (kh == 0 && t < 255)
            nxc2 = *(const vf2*)(xgb + (d ? tt - 1 : tt + 1) * 512 + 2 * cp);
        vf2 a0 = xc2 + bias2, a1 = {0.f, 0.f};
#pragma unroll
        for (int r = 0; r < 36; ++r) {  // LDS rows: k = r
            float hs = rl(h, r);
            vf2 hb = {hs, hs};
            vf2 w = *(const vf2*)(wl + r * 512);
            if (r & 1) a1 = __builtin_elementwise_fma(hb, w, a1);
            else       a0 = __builtin_elementwise_fma(hb, w, a0);
        }
#pragma unroll
        for (int r = 0; r < 28; ++r) {  // global rows: k = 36 + r
            float hs = rl(h, 36 + r);
            vf2 hb = {hs, hs};
            vf2 w = *(const vf2*)(wpg + r * 512);
            if (r & 1) a1 = __builtin_elementwise_fma(hb, w, a1);
            else       a0 = __builtin_elementwise_fma(hb, w, a0);
        }
        *(vf2*)&part[t & 1][kh * 512 + 2 * cp] = a0 + a1;
        __syncthreads();
        const float* p = part[t & 1];
        float iv = p[n]       + p[512 + n];
        float fv = p[128 + n] + p[512 + 128 + n];
        float gv = p[256 + n] + p[512 + 256 + n];
        float ov = p[384 + n] + p[512 + 384 + n];
        cst = sigf(fv) * cst + sigf(iv) * tanhfast(gv);
        h = sigf(ov) * tanhfast(cst);
        if (cp < 64) sfb[tt * 256 + n] = h;   // waves 0 and 4 store n=0..127
        xc2 = nxc2;
    }
}

// ---------------- RGN recurrence: 768 thr, replicated tail, 1 barrier --------
// (R1 form: best measured for RGN)
__global__ __launch_bounds__(768) void rgn_rec_k(const float* __restrict__ xg,
                                                 const float* __restrict__ Wh,
                                                 const float* __restrict__ state0,
                                                 const float* __restrict__ state1,
                                                 float* __restrict__ outbase)
{
    int b = blockIdx.x, d = blockIdx.y;
    int tid = threadIdx.x, lane = tid & 63;
    int kh = (tid >= 384) ? 1 : 0;      // wave-uniform (384 = 6 waves)
    int c  = tid - kh * 384;            // gate column 0..383
    const float* Whz = Wh + (long long)d * 49152;   // [128][384]
    const float* wp = Whz + (long long)(kh * 64) * 384 + c;
    vf16 W0, W1, W2, W3;
    LD16(W0, wp + 0 * 16 * 384, 384); LD16(W1, wp + 1 * 16 * 384, 384);
    LD16(W2, wp + 2 * 16 * 384, 384); LD16(W3, wp + 3 * 16 * 384, 384);

    __shared__ float part[2][768];
    int n = kh * 64 + lane;             // h element this lane replicates
    const float* st = d ? state1 : state0;
    float h = st[b * 128 + n];
    const float* xgb = xg + (long long)d * 6291456 + (long long)b * 98304;
    int tt0 = d ? 255 : 0;
    const float* xr0 = xgb + tt0 * 384;
    float x_r = xr0[n], x_z = xr0[128 + n], x_n = xr0[256 + n];

#pragma unroll 1
    for (int t = 0; t < 256; ++t) {
        int tt = d ? 255 - t : t;
        float nx_r = 0, nx_z = 0, nx_n = 0;
        if (t < 255) {
            const float* xr = xgb + (d ? tt - 1 : tt + 1) * 384;
            nx_r = xr[n]; nx_z = xr[128 + n]; nx_n = xr[256 + n];
        }
        float s0 = 0.f, s1 = 0.f, s2 = 0.f, s3 = 0.f;
        DOT16(s0, W0, h, 0);  DOT16(s1, W1, h, 16);
        DOT16(s2, W2, h, 32); DOT16(s3, W3, h, 48);
        part[t & 1][kh * 384 + c] = (s0 + s1) + (s2 + s3);
        __syncthreads();
        const float* p = part[t & 1];
        float pr = p[n]       + p[384 + n];
        float pz = p[128 + n] + p[384 + 128 + n];
        float pn = p[256 + n] + p[384 + 256 + n];
        float r  = sigf(x_r + pr);
        float zz = sigf(x_z + pz);
        float nn = tanhfast(x_n + r * pn);       // RGN: no hidden bias
        h = (1.f - zz) * nn + zz * h;
        x_r = nx_r; x_z = nx_z; x_n = nx_n;
    }
    if (c < 64) outbase[(long long)d * 8192 + b * 128 + n] = h;  // waves 0 & 6
}

// ---------------- final FC ----------------
__global__ __launch_bounds__(256) void fc_k(const float* __restrict__ o01,
                                            const float* __restrict__ f1W,
                                            const float* __restrict__ f1b,
                                            const float* __restrict__ f2W,
                                            const float* __restrict__ f2b,
                                            float* __restrict__ out)
{
    __shared__ float s[8192];
    __shared__ float h1[2048];
    int tid = threadIdx.x;
    for (int e = tid; e < 8192; e += 256) s[e] = o01[e] + o01[8192 + e];
    __syncthreads();
    for (int o = tid; o < 2048; o += 256) {
        int b = o >> 5, q = o & 31;
        float acc = f1b[q];
        for (int k = 0; k < 128; ++k) acc += s[b * 128 + k] * f1W[k * 32 + q];
        h1[o] = acc >= 0.f ? acc : 0.01f * acc;
    }
    __syncthreads();
    if (tid < 64) {
        float acc = f2b[0];
        for (int q = 0; q < 32; ++q) acc += h1[tid * 32 + q] * f2W[q];
        out[tid] = acc;
    }
}

// ============================ launch =========================================
extern "C" void kernel_launch(void* const* d_in, const int* in_sizes, int n_in,
                              void* d_out, int out_size, void* d_ws, size_t ws_size,
                              hipStream_t stream)
{
    const int*   sent     = (const int*)  d_in[0];
    const float* acoustic = (const float*)d_in[1];
    const float* video    = (const float*)d_in[2];
    const float* state0   = (const float*)d_in[3];
    const float* state1   = (const float*)d_in[4];
    const float* emb      = (const float*)d_in[5];
    const float* plW = (const float*)d_in[6],  *plb = (const float*)d_in[7];
    const float* paW = (const float*)d_in[8],  *pab = (const float*)d_in[9];
    const float* pvW = (const float*)d_in[10], *pvb = (const float*)d_in[11];
    const float* gWi = (const float*)d_in[12], *gWh = (const float*)d_in[13];
    const float* gbi = (const float*)d_in[14], *gbh = (const float*)d_in[15];
    const float* lWi = (const float*)d_in[16], *lWh = (const float*)d_in[17];
    const float* lbi = (const float*)d_in[18], *lbh = (const float*)d_in[19];
    const float* rWx = (const float*)d_in[20], *rWh = (const float*)d_in[21];
    const float* rb  = (const float*)d_in[22];
    const float* f1W = (const float*)d_in[23], *f1b = (const float*)d_in[24];
    const float* f2W = (const float*)d_in[25], *f2b = (const float*)d_in[26];
    float* ws  = (float*)d_ws;
    float* out = (float*)d_out;

    dim3 blk(64);

    // fused modality projections -> seq[3][16384][128]  (one launch)
    proj3_k<<<dim3(2, 256, 3), blk, 0, stream>>>(sent, emb, acoustic, video,
        plW, plb, paW, pab, pvW, pvb, ws + WS_SEQ);

    // GRU input projections, z = modality*2 + dir
    gemm_k<<<dim3(3, 256, 6), blk, 0, stream>>>(ws + WS_SEQ, 2097152, 2, 128, nullptr,
        gWi, 24576, 192, 0, gbi, 192, ws + WS_XGGRU, 3145728, 192, 128, 1.f, 0);

    // GRU recurrences -> x[3][16384][128]
    gru_rec_k<<<dim3(64, 6), dim3(192), 0, stream>>>(ws + WS_XGGRU, gWh, gbh, ws + WS_X);

    // attention: round 1 initializes tstep = x + att1, round 2 accumulates
    att_score_k<<<dim3(4, 4, 192), blk, 0, stream>>>(ws + WS_X, ws + WS_S,
        0, 1, 2, 1, 0, 0);
    softmax_k<<<dim3(12288), dim3(256), 0, stream>>>(ws + WS_S);
    att_apply_k<<<dim3(2, 4, 192), blk, 0, stream>>>(ws + WS_S, ws + WS_X,
        ws + WS_TSTEP, 0, 1, 2, 1, 0, 0, 1);
    att_score_k<<<dim3(4, 4, 192), blk, 0, stream>>>(ws + WS_X, ws + WS_S,
        0, 1, 2, 2, 2, 1);
    softmax_k<<<dim3(12288), dim3(256), 0, stream>>>(ws + WS_S);
    att_apply_k<<<dim3(2, 4, 192), blk, 0, stream>>>(ws + WS_S, ws + WS_X,
        ws + WS_TSTEP, 0, 1, 2, 2, 2, 1, 0);

    // LSTM input projections
    gemm_k<<<dim3(8, 256, 2), blk, 0, stream>>>(ws + WS_TSTEP, 0, 1, 384, nullptr,
        lWi, 196608, 512, 0, lbi, 512, ws + WS_XGLSTM, 8388608, 512, 384, 1.f, 0);

    // BiLSTM recurrences -> step_fusion[16384][256]
    lstm_rec_k<<<dim3(64, 2), dim3(512), 0, stream>>>(ws + WS_XGLSTM, lWh, lbh, ws + WS_SF);

    // RGN input projections
    gemm_k<<<dim3(6, 256, 2), blk, 0, stream>>>(ws + WS_SF, 0, 1, 256, nullptr,
        rWx, 98304, 384, 0, rb, 384, ws + WS_XGRGN, 6291456, 384, 256, 1.f, 0);

    // RGN recurrences -> out0/out1 [64][128]
    rgn_rec_k<<<dim3(64, 2), dim3(768), 0, stream>>>(ws + WS_XGRGN, rWh, state0, state1,
                                                     ws + WS_OUT0);

    // final FC -> d_out [64]
    fc_k<<<dim3(1), dim3(256), 0, stream>>>(ws + WS_OUT0, f1W, f1b, f2W, f2b, out);
}